// Round 1
// baseline (357.147 us; speedup 1.0000x reference)
//
#include <hip/hip_runtime.h>
#include <hip/hip_bf16.h>

// Problem constants
#define B_    2
#define S_    2048
#define E_    1024
#define H_    16
#define HD_   64
#define M_    (B_ * S_)     // 4096 rows of x
#define QKVN  (3 * E_)      // 3072

typedef __attribute__((ext_vector_type(8))) short  short8;
typedef __attribute__((ext_vector_type(4))) float  f32x4;

static __device__ __forceinline__ unsigned short f2bf(float f) {
  union { float f; unsigned int u; } c; c.f = f;
  unsigned int u = c.u;
  return (unsigned short)((u + 0x7fffu + ((u >> 16) & 1u)) >> 16);  // RNE
}

// ---------------------------------------------------------------------------
// fp32 -> bf16 convert (vectorized, 4 elems/thread)
// ---------------------------------------------------------------------------
__global__ __launch_bounds__(256) void cvt_f32_to_bf16(
    const float* __restrict__ in, unsigned short* __restrict__ out, int n4) {
  int i = blockIdx.x * 256 + threadIdx.x;
  if (i < n4) {
    float4 v = reinterpret_cast<const float4*>(in)[i];
    ushort4 r;
    r.x = f2bf(v.x); r.y = f2bf(v.y); r.z = f2bf(v.z); r.w = f2bf(v.w);
    reinterpret_cast<ushort4*>(out)[i] = r;
  }
}

// ---------------------------------------------------------------------------
// C[M,N] = A(MxK, row-major) * Bt(NxK, row-major)^T
// 128x128 tile, BK=64, 4 waves (2x2), each wave 64x64 via 4x4 16x16x32 MFMA.
// LDS XOR-swizzled (byte ^= (row&7)<<4) so ds_read_b128 is conflict-free.
// BF16_OUT=1: store bf16 (no bias). BF16_OUT=0: store fp32 + bias.
// ---------------------------------------------------------------------------
template <int BF16_OUT>
__global__ __launch_bounds__(256) void gemm_bt(
    const unsigned short* __restrict__ A, const unsigned short* __restrict__ Bt,
    void* __restrict__ Cout, const float* __restrict__ bias,
    int M, int N, int K, int ldc) {
  __shared__ alignas(16) unsigned short lds_a[128 * 64];  // 16 KB
  __shared__ alignas(16) unsigned short lds_b[128 * 64];  // 16 KB
  const int t  = threadIdx.x;
  const int w  = t >> 6, l = t & 63, g = l >> 4, lr = l & 15;
  const int bm = blockIdx.y * 128, bn = blockIdx.x * 128;
  const int wr = (w >> 1) * 64,  wc = (w & 1) * 64;

  f32x4 acc[4][4] = {};

  for (int k0 = 0; k0 < K; k0 += 64) {
    __syncthreads();
    // Stage A-tile [128][64] and B-tile [128][64] (bf16): 1024 16B chunks each,
    // 4 per thread, coalesced 16B global loads, swizzled ds_write_b128.
#pragma unroll
    for (int i = 0; i < 4; i++) {
      const int r  = i * 32 + (t >> 3);
      const int kc = t & 7;
      const int off = ((r * 128 + kc * 16) ^ ((r & 7) << 4));
      *(short8*)((char*)lds_a + off) =
          *(const short8*)(A + (size_t)(bm + r) * K + k0 + kc * 8);
      *(short8*)((char*)lds_b + off) =
          *(const short8*)(Bt + (size_t)(bn + r) * K + k0 + kc * 8);
    }
    __syncthreads();

    short8 af[4][2], bfr[4][2];
#pragma unroll
    for (int m = 0; m < 4; m++) {
      const int R = wr + m * 16 + lr;
#pragma unroll
      for (int kk = 0; kk < 2; kk++)
        af[m][kk] = *(const short8*)((const char*)lds_a +
            ((R * 128 + kk * 64 + g * 16) ^ ((R & 7) << 4)));
    }
#pragma unroll
    for (int n = 0; n < 4; n++) {
      const int R = wc + n * 16 + lr;
#pragma unroll
      for (int kk = 0; kk < 2; kk++)
        bfr[n][kk] = *(const short8*)((const char*)lds_b +
            ((R * 128 + kk * 64 + g * 16) ^ ((R & 7) << 4)));
    }
#pragma unroll
    for (int m = 0; m < 4; m++)
#pragma unroll
      for (int n = 0; n < 4; n++) {
        acc[m][n] = __builtin_amdgcn_mfma_f32_16x16x32_bf16(
            af[m][0], bfr[n][0], acc[m][n], 0, 0, 0);
        acc[m][n] = __builtin_amdgcn_mfma_f32_16x16x32_bf16(
            af[m][1], bfr[n][1], acc[m][n], 0, 0, 0);
      }
  }

  // Epilogue: C/D layout col = lane&15, row = (lane>>4)*4 + j  [m89-verified]
#pragma unroll
  for (int m = 0; m < 4; m++)
#pragma unroll
    for (int n = 0; n < 4; n++)
#pragma unroll
      for (int j = 0; j < 4; j++) {
        const int row = bm + wr + m * 16 + g * 4 + j;
        const int col = bn + wc + n * 16 + lr;
        const float v = acc[m][n][j];
        if constexpr (BF16_OUT) {
          ((unsigned short*)Cout)[(size_t)row * ldc + col] = f2bf(v);
        } else {
          ((float*)Cout)[(size_t)row * ldc + col] = v + bias[col];
        }
      }
}

// ---------------------------------------------------------------------------
// Causal flash attention over interleaved qkv (bf16, layout (B,S,H,3,HD)).
// Grid: (S/64, B*H). 4 waves/block, 16 q-rows per wave, KV tiles of 32 rows.
// K staged [32][64], V staged transposed [64][32], both XOR-swizzled.
// P re-fragmented through per-wave LDS buffer for the PV MFMA.
// Output written to attn_out as (B,S,E) bf16 with head-major cols h*64+d.
// ---------------------------------------------------------------------------
__global__ __launch_bounds__(256) void attn_fwd(
    const unsigned short* __restrict__ qkv, unsigned short* __restrict__ attn_out) {
  __shared__ alignas(16) unsigned short lds_k[32 * 64];    // 4 KB  [kv][d]
  __shared__ alignas(16) unsigned short lds_vt[64 * 32];   // 4 KB  [d][kv]
  __shared__ alignas(16) unsigned short lds_p[4][16 * 32]; // 4 KB  per-wave P

  const int t = threadIdx.x;
  const int w = t >> 6, l = t & 63, g = l >> 4, lr = l & 15;
  const int bh = blockIdx.y, b = bh >> 4, h = bh & 15;
  const int q0 = blockIdx.x * 64;
  const int qw = q0 + w * 16;
  const unsigned short* base = qkv + (size_t)b * S_ * QKVN + h * (3 * HD_);

  // Q fragments (A-side, 16 rows x 64 d): lane holds Q[lr][(g*8..+8) + 32*kk]
  short8 qf[2];
  {
    const unsigned short* qp = base + (size_t)(qw + lr) * QKVN + g * 8;
    qf[0] = *(const short8*)qp;
    qf[1] = *(const short8*)(qp + 32);
  }

  f32x4 o[4] = {};
  float m_r[4], l_r[4];
#pragma unroll
  for (int j = 0; j < 4; j++) { m_r[j] = -3.0e38f; l_r[j] = 0.f; }

  const int numt = 2 * blockIdx.x + 2;  // KV tiles of 32 up to q0+63
  for (int kt = 0; kt < numt; kt++) {
    const int k0 = kt * 32;
    __syncthreads();
    {
      // stage K[32][64] (swizzled row-major) and V^T[64][32] (swizzled)
      const int r = t >> 3, kc = t & 7;
      const unsigned short* kp = base + (size_t)(k0 + r) * QKVN + HD_ + kc * 8;
      short8 kvv = *(const short8*)kp;
      const int off = ((r * 128 + kc * 16) ^ ((r & 7) << 4));
      *(short8*)((char*)lds_k + off) = kvv;
      short8 vvv = *(const short8*)(kp + HD_);
#pragma unroll
      for (int j = 0; j < 8; j++) {
        const int d = kc * 8 + j;
        const int offv = ((d * 64 + r * 2) ^ ((d & 7) << 4));
        *(unsigned short*)((char*)lds_vt + offv) = (unsigned short)vvv[j];
      }
    }
    __syncthreads();

    // scores: S[16 q][32 kv] = Q(16x64) . K^T, two 16-col MFMA tiles
    f32x4 s[2];
#pragma unroll
    for (int n = 0; n < 2; n++) {
      const int R = n * 16 + lr;  // kv row within tile (B-frag col)
      short8 bk0 = *(const short8*)((const char*)lds_k +
          ((R * 128 + g * 16) ^ ((R & 7) << 4)));
      short8 bk1 = *(const short8*)((const char*)lds_k +
          ((R * 128 + 64 + g * 16) ^ ((R & 7) << 4)));
      f32x4 z = {};
      z = __builtin_amdgcn_mfma_f32_16x16x32_bf16(qf[0], bk0, z, 0, 0, 0);
      z = __builtin_amdgcn_mfma_f32_16x16x32_bf16(qf[1], bk1, z, 0, 0, 0);
      s[n] = z;
    }

    // online softmax (per q-row; rows live in 16-lane groups)
    float cs[4], p0[4], p1[4];
#pragma unroll
    for (int j = 0; j < 4; j++) {
      const int qrow = qw + g * 4 + j;
      float s0 = s[0][j] * 0.125f;             // scale = hd^-0.5
      float s1 = s[1][j] * 0.125f;
      if (k0 + lr > qrow)      s0 = -3.0e38f;  // causal mask
      if (k0 + 16 + lr > qrow) s1 = -3.0e38f;
      float mx = fmaxf(s0, s1);
#pragma unroll
      for (int dd = 8; dd >= 1; dd >>= 1) mx = fmaxf(mx, __shfl_xor(mx, dd, 16));
      const float mn = fmaxf(m_r[j], mx);
      const float c  = __expf(m_r[j] - mn);
      const float e0 = __expf(s0 - mn);
      const float e1 = __expf(s1 - mn);
      float sum = e0 + e1;
#pragma unroll
      for (int dd = 8; dd >= 1; dd >>= 1) sum += __shfl_xor(sum, dd, 16);
      l_r[j] = l_r[j] * c + sum;
      m_r[j] = mn;
      cs[j] = c; p0[j] = e0; p1[j] = e1;
    }
#pragma unroll
    for (int c4 = 0; c4 < 4; c4++) {
      f32x4 tmp = o[c4];
      tmp[0] *= cs[0]; tmp[1] *= cs[1]; tmp[2] *= cs[2]; tmp[3] *= cs[3];
      o[c4] = tmp;
    }

    // P (16x32) -> per-wave LDS (bf16, swizzled), then re-read as A-fragment
#pragma unroll
    for (int j = 0; j < 4; j++) {
      const int row = g * 4 + j;
      *(unsigned short*)((char*)lds_p[w] +
          ((row * 64 + lr * 2) ^ ((row & 7) << 4))) = f2bf(p0[j]);
      *(unsigned short*)((char*)lds_p[w] +
          ((row * 64 + 32 + lr * 2) ^ ((row & 7) << 4))) = f2bf(p1[j]);
    }
    __asm__ volatile("s_waitcnt lgkmcnt(0)" ::: "memory");

    short8 pf = *(const short8*)((const char*)lds_p[w] +
        ((lr * 64 + g * 16) ^ ((lr & 7) << 4)));
#pragma unroll
    for (int c4 = 0; c4 < 4; c4++) {
      const int R = c4 * 16 + lr;  // output d (B-frag col)
      short8 vf = *(const short8*)((const char*)lds_vt +
          ((R * 64 + g * 16) ^ ((R & 7) << 4)));
      o[c4] = __builtin_amdgcn_mfma_f32_16x16x32_bf16(pf, vf, o[c4], 0, 0, 0);
    }
  }

  // epilogue: O / l, write bf16 to (B,S,E)
  unsigned short* outp = attn_out + (size_t)b * S_ * E_ + h * HD_;
#pragma unroll
  for (int j = 0; j < 4; j++) {
    const float inv = 1.0f / l_r[j];
    const int qrow = qw + g * 4 + j;
#pragma unroll
    for (int c4 = 0; c4 < 4; c4++)
      outp[(size_t)qrow * E_ + c4 * 16 + lr] = f2bf(o[c4][j] * inv);
  }
}

// ---------------------------------------------------------------------------
extern "C" void kernel_launch(void* const* d_in, const int* in_sizes, int n_in,
                              void* d_out, int out_size, void* d_ws, size_t ws_size,
                              hipStream_t stream) {
  (void)in_sizes; (void)n_in; (void)out_size; (void)ws_size;
  const float* x      = (const float*)d_in[0];
  const float* w_qkv  = (const float*)d_in[1];
  const float* w_proj = (const float*)d_in[2];
  const float* b_proj = (const float*)d_in[3];
  float* out = (float*)d_out;

  // workspace layout (all bf16):
  unsigned short* x_bf     = (unsigned short*)d_ws;                 // 4096x1024
  unsigned short* wqkv_bf  = x_bf    + (size_t)M_ * E_;             // 3072x1024
  unsigned short* wproj_bf = wqkv_bf + (size_t)QKVN * E_;           // 1024x1024
  unsigned short* qkv_bf   = wproj_bf + (size_t)E_ * E_;            // 4096x3072
  unsigned short* attn_bf  = qkv_bf  + (size_t)M_ * QKVN;           // 4096x1024

  int n4;
  n4 = M_ * E_ / 4;
  cvt_f32_to_bf16<<<(n4 + 255) / 256, 256, 0, stream>>>(x, x_bf, n4);
  n4 = QKVN * E_ / 4;
  cvt_f32_to_bf16<<<(n4 + 255) / 256, 256, 0, stream>>>(w_qkv, wqkv_bf, n4);
  n4 = E_ * E_ / 4;
  cvt_f32_to_bf16<<<(n4 + 255) / 256, 256, 0, stream>>>(w_proj, wproj_bf, n4);

  // QKV projection: (4096x1024) @ (3072x1024)^T -> bf16 (4096x3072)
  gemm_bt<1><<<dim3(QKVN / 128, M_ / 128), 256, 0, stream>>>(
      x_bf, wqkv_bf, (void*)qkv_bf, nullptr, M_, QKVN, E_, QKVN);

  // causal attention
  attn_fwd<<<dim3(S_ / 64, B_ * H_), 256, 0, stream>>>(qkv_bf, attn_bf);

  // output projection + bias: (4096x1024) @ (1024x1024)^T + b -> fp32 d_out
  gemm_bt<0><<<dim3(E_ / 128, M_ / 128), 256, 0, stream>>>(
      attn_bf, wproj_bf, (void*)out, b_proj, M_, E_, E_, E_);
}

// Round 2
// 244.056 us; speedup vs baseline: 1.4634x; 1.4634x over previous
//
#include <hip/hip_runtime.h>
#include <hip/hip_bf16.h>

// Problem constants
#define B_    2
#define S_    2048
#define E_    1024
#define H_    16
#define HD_   64
#define M_    (B_ * S_)     // 4096 rows of x
#define QKVN  (3 * E_)      // 3072

typedef __attribute__((ext_vector_type(8))) short  short8;
typedef __attribute__((ext_vector_type(4))) float  f32x4;

static __device__ __forceinline__ unsigned short f2bf(float f) {
  union { float f; unsigned int u; } c; c.f = f;
  unsigned int u = c.u;
  return (unsigned short)((u + 0x7fffu + ((u >> 16) & 1u)) >> 16);  // RNE
}

// async global->LDS, 16B per lane; LDS dest must be wave-uniform base (+lane*16)
static __device__ __forceinline__ void gload16(unsigned short* lds,
                                               const unsigned short* g) {
  __builtin_amdgcn_global_load_lds(
      (__attribute__((address_space(1))) void*)g,
      (__attribute__((address_space(3))) void*)lds, 16, 0, 0);
}

// ---------------------------------------------------------------------------
// fp32 -> bf16 convert (vectorized, 4 elems/thread)
// ---------------------------------------------------------------------------
__global__ __launch_bounds__(256) void cvt_f32_to_bf16(
    const float* __restrict__ in, unsigned short* __restrict__ out, int n4) {
  int i = blockIdx.x * 256 + threadIdx.x;
  if (i < n4) {
    float4 v = reinterpret_cast<const float4*>(in)[i];
    ushort4 r;
    r.x = f2bf(v.x); r.y = f2bf(v.y); r.z = f2bf(v.z); r.w = f2bf(v.w);
    reinterpret_cast<ushort4*>(out)[i] = r;
  }
}

// ---------------------------------------------------------------------------
// C[M,N] = A(MxK, row-major) * Bt(NxK, row-major)^T
// 128x128 tile, BK=64, 4 waves (2x2), each wave 64x64 via 4x4 16x16x32 MFMA.
// Staging via global_load_lds width=16: linear LDS dest, PRE-SWIZZLED global
// source chunk (c ^ (r&7)), swizzled ds_read_b128 on the consume side.
// ---------------------------------------------------------------------------
template <int BF16_OUT>
__global__ __launch_bounds__(256) void gemm_bt(
    const unsigned short* __restrict__ A, const unsigned short* __restrict__ Bt,
    void* __restrict__ Cout, const float* __restrict__ bias,
    int M, int N, int K, int ldc) {
  __shared__ alignas(16) unsigned short lds_a[128 * 64];  // 16 KB
  __shared__ alignas(16) unsigned short lds_b[128 * 64];  // 16 KB
  const int t  = threadIdx.x;
  const int w  = t >> 6, l = t & 63, g = l >> 4, lr = l & 15;
  const int bm = blockIdx.y * 128, bn = blockIdx.x * 128;
  const int wr = (w >> 1) * 64,  wc = (w & 1) * 64;

  f32x4 acc[4][4] = {};

  for (int k0 = 0; k0 < K; k0 += 64) {
    __syncthreads();
    // Stage A-tile [128][64] and B-tile [128][64]: 16 wave-passes of 1024B.
#pragma unroll
    for (int i = 0; i < 4; i++) {
      const int pass = w * 4 + i;            // 0..15 (wave-uniform)
      const int r = pass * 8 + (l >> 3);     // 0..127
      const int c = (l & 7) ^ (r & 7);       // pre-swizzled source chunk
      gload16(lds_a + pass * 512, A + (size_t)(bm + r) * K + k0 + c * 8);
      gload16(lds_b + pass * 512, Bt + (size_t)(bn + r) * K + k0 + c * 8);
    }
    __syncthreads();

    short8 af[4][2], bfr[4][2];
#pragma unroll
    for (int m = 0; m < 4; m++) {
      const int R = wr + m * 16 + lr;
#pragma unroll
      for (int kk = 0; kk < 2; kk++)
        af[m][kk] = *(const short8*)((const char*)lds_a +
            ((R * 128 + kk * 64 + g * 16) ^ ((R & 7) << 4)));
    }
#pragma unroll
    for (int n = 0; n < 4; n++) {
      const int R = wc + n * 16 + lr;
#pragma unroll
      for (int kk = 0; kk < 2; kk++)
        bfr[n][kk] = *(const short8*)((const char*)lds_b +
            ((R * 128 + kk * 64 + g * 16) ^ ((R & 7) << 4)));
    }
#pragma unroll
    for (int m = 0; m < 4; m++)
#pragma unroll
      for (int n = 0; n < 4; n++) {
        acc[m][n] = __builtin_amdgcn_mfma_f32_16x16x32_bf16(
            af[m][0], bfr[n][0], acc[m][n], 0, 0, 0);
        acc[m][n] = __builtin_amdgcn_mfma_f32_16x16x32_bf16(
            af[m][1], bfr[n][1], acc[m][n], 0, 0, 0);
      }
  }

  // Epilogue: C/D layout col = lane&15, row = (lane>>4)*4 + j  [m89-verified]
#pragma unroll
  for (int m = 0; m < 4; m++)
#pragma unroll
    for (int n = 0; n < 4; n++)
#pragma unroll
      for (int j = 0; j < 4; j++) {
        const int row = bm + wr + m * 16 + g * 4 + j;
        const int col = bn + wc + n * 16 + lr;
        const float v = acc[m][n][j];
        if constexpr (BF16_OUT) {
          ((unsigned short*)Cout)[(size_t)row * ldc + col] = f2bf(v);
        } else {
          ((float*)Cout)[(size_t)row * ldc + col] = v + bias[col];
        }
      }
}

// ---------------------------------------------------------------------------
// Causal flash attention over interleaved qkv (bf16, layout (B,S,H,3,HD)).
// Grid: 512 blocks (1D, causal work-pairing remap), 4 waves/block,
// 32 q-rows per wave (128/block), KV tiles of 64 rows.
// K staged [64][64] (swz (r&7)<<4); V^T staged [64][64]
// (swz ((d&7)^((d>>3)&7))<<4 -- conflict-free on BOTH write and read sides).
// P re-fragmented through per-wave LDS buffer [32][64] for the PV MFMA.
// ---------------------------------------------------------------------------
__global__ __launch_bounds__(256) void attn_fwd(
    const unsigned short* __restrict__ qkv, unsigned short* __restrict__ attn_out) {
  __shared__ alignas(16) unsigned short lds_k[64 * 64];     // 8 KB  [kv][d]
  __shared__ alignas(16) unsigned short lds_vt[64 * 64];    // 8 KB  [d][kv]
  __shared__ alignas(16) unsigned short lds_p[4][32 * 64];  // 16 KB per-wave P

  const int t = threadIdx.x;
  const int w = t >> 6, l = t & 63, g = l >> 4, lr = l & 15;
  const int bid = blockIdx.x;
  const int bh = bid & 31, b = bh >> 4, h = bh & 15;
  const int rr = bid >> 5;                       // 0..15
  const int bx = (rr < 8) ? rr : 23 - rr;        // pair light+heavy per CU
  const int q0 = bx * 128;
  const int qw = q0 + w * 32;
  const unsigned short* base = qkv + (size_t)b * S_ * QKVN + h * (3 * HD_);

  // Q fragments: A-side, lane (g,lr): Q[qw+m*16+lr][g*8 + kk*32 + 0..7]
  short8 qf[2][2];
#pragma unroll
  for (int m = 0; m < 2; m++) {
    const unsigned short* qp = base + (size_t)(qw + m * 16 + lr) * QKVN + g * 8;
    qf[m][0] = *(const short8*)qp;
    qf[m][1] = *(const short8*)(qp + 32);
  }

  f32x4 o[2][4] = {};
  float m_r[2][4], l_r[2][4];
#pragma unroll
  for (int m = 0; m < 2; m++)
#pragma unroll
    for (int j = 0; j < 4; j++) { m_r[m][j] = -3.0e38f; l_r[m][j] = 0.f; }

  const int numt = 2 * bx + 2;  // 64-wide KV tiles covering kv < q0+128
  for (int kt = 0; kt < numt; kt++) {
    const int k0 = kt * 64;
    __syncthreads();
    // ---- stage K[64][64] and V^T[64][64] (two 32-row passes) ----
#pragma unroll
    for (int p = 0; p < 2; p++) {
      const int r  = p * 32 + (t >> 3);
      const int kc = t & 7;
      const unsigned short* kp = base + (size_t)(k0 + r) * QKVN + HD_ + kc * 8;
      short8 kv8 = *(const short8*)kp;
      *(short8*)((char*)lds_k + ((r * 128 + kc * 16) ^ ((r & 7) << 4))) = kv8;
      short8 vv8 = *(const short8*)(kp + HD_);
#pragma unroll
      for (int j = 0; j < 8; j++) {
        const int d = kc * 8 + j;
        const int swz = ((d & 7) ^ ((d >> 3) & 7)) << 4;
        *(unsigned short*)((char*)lds_vt + ((d * 128 + r * 2) ^ swz)) =
            (unsigned short)vv8[j];
      }
    }
    __syncthreads();

    // ---- scores S[32 q][64 kv] ----
    f32x4 s[2][4];
    __builtin_amdgcn_s_setprio(1);
#pragma unroll
    for (int n = 0; n < 4; n++) {
      const int R = n * 16 + lr;
      short8 b0 = *(const short8*)((const char*)lds_k +
          ((R * 128 + g * 16) ^ ((R & 7) << 4)));
      short8 b1 = *(const short8*)((const char*)lds_k +
          ((R * 128 + 64 + g * 16) ^ ((R & 7) << 4)));
#pragma unroll
      for (int m = 0; m < 2; m++) {
        f32x4 z = {};
        z = __builtin_amdgcn_mfma_f32_16x16x32_bf16(qf[m][0], b0, z, 0, 0, 0);
        z = __builtin_amdgcn_mfma_f32_16x16x32_bf16(qf[m][1], b1, z, 0, 0, 0);
        s[m][n] = z;
      }
    }
    __builtin_amdgcn_s_setprio(0);

    // ---- causal mask (only tiles that touch the diagonal of this wave) ----
    if (k0 + 63 > qw) {
#pragma unroll
      for (int m = 0; m < 2; m++)
#pragma unroll
        for (int n = 0; n < 4; n++) {
          const int kvc = k0 + n * 16 + lr;
#pragma unroll
          for (int j = 0; j < 4; j++) {
            const int qrow = qw + m * 16 + g * 4 + j;
            if (kvc > qrow) s[m][n][j] = -3.0e38f;
          }
        }
    }

    // ---- online softmax (rows live in 16-lane groups) + P -> LDS ----
#pragma unroll
    for (int m = 0; m < 2; m++) {
#pragma unroll
      for (int j = 0; j < 4; j++) {
        const float v0 = s[m][0][j] * 0.125f, v1 = s[m][1][j] * 0.125f;
        const float v2 = s[m][2][j] * 0.125f, v3 = s[m][3][j] * 0.125f;
        float mx = fmaxf(fmaxf(v0, v1), fmaxf(v2, v3));
#pragma unroll
        for (int dd = 8; dd; dd >>= 1) mx = fmaxf(mx, __shfl_xor(mx, dd, 16));
        const float mn = fmaxf(m_r[m][j], mx);
        const float c  = __expf(m_r[m][j] - mn);
        m_r[m][j] = mn;
        const float e0 = __expf(v0 - mn), e1 = __expf(v1 - mn);
        const float e2 = __expf(v2 - mn), e3 = __expf(v3 - mn);
        float sum = (e0 + e1) + (e2 + e3);
#pragma unroll
        for (int dd = 8; dd; dd >>= 1) sum += __shfl_xor(sum, dd, 16);
        l_r[m][j] = l_r[m][j] * c + sum;
#pragma unroll
        for (int dt = 0; dt < 4; dt++) o[m][dt][j] *= c;
        const int row = m * 16 + g * 4 + j;
        const int sw  = (row & 7) << 4;
        char* pb = (char*)lds_p[w];
        *(unsigned short*)(pb + ((row * 128 +      lr * 2) ^ sw)) = f2bf(e0);
        *(unsigned short*)(pb + ((row * 128 + 32 + lr * 2) ^ sw)) = f2bf(e1);
        *(unsigned short*)(pb + ((row * 128 + 64 + lr * 2) ^ sw)) = f2bf(e2);
        *(unsigned short*)(pb + ((row * 128 + 96 + lr * 2) ^ sw)) = f2bf(e3);
      }
    }
    // per-wave LDS round-trip: wait for this wave's ds_writes
    __asm__ volatile("s_waitcnt lgkmcnt(0)" ::: "memory");

    // ---- PV: O[32 q][64 d] += P(32x64) @ V(64x64) ----
    __builtin_amdgcn_s_setprio(1);
#pragma unroll
    for (int m = 0; m < 2; m++) {
      const int prow = m * 16 + lr;
      const int psw  = (prow & 7) << 4;
      short8 pf0 = *(const short8*)((const char*)lds_p[w] +
          ((prow * 128 + g * 16) ^ psw));
      short8 pf1 = *(const short8*)((const char*)lds_p[w] +
          ((prow * 128 + 64 + g * 16) ^ psw));
#pragma unroll
      for (int dt = 0; dt < 4; dt++) {
        const int R = dt * 16 + lr;
        const int vsw = ((R & 7) ^ ((R >> 3) & 7)) << 4;
        short8 vf0 = *(const short8*)((const char*)lds_vt +
            ((R * 128 + g * 16) ^ vsw));
        short8 vf1 = *(const short8*)((const char*)lds_vt +
            ((R * 128 + 64 + g * 16) ^ vsw));
        o[m][dt] = __builtin_amdgcn_mfma_f32_16x16x32_bf16(pf0, vf0, o[m][dt], 0, 0, 0);
        o[m][dt] = __builtin_amdgcn_mfma_f32_16x16x32_bf16(pf1, vf1, o[m][dt], 0, 0, 0);
      }
    }
    __builtin_amdgcn_s_setprio(0);
  }

  // ---- epilogue: O / l, write bf16 to (B,S,E) ----
  unsigned short* outp = attn_out + (size_t)b * S_ * E_ + h * HD_;
#pragma unroll
  for (int m = 0; m < 2; m++)
#pragma unroll
    for (int j = 0; j < 4; j++) {
      const float inv = 1.0f / l_r[m][j];
      const int qrow = qw + m * 16 + g * 4 + j;
#pragma unroll
      for (int dt = 0; dt < 4; dt++)
        outp[(size_t)qrow * E_ + dt * 16 + lr] = f2bf(o[m][dt][j] * inv);
    }
}

// ---------------------------------------------------------------------------
extern "C" void kernel_launch(void* const* d_in, const int* in_sizes, int n_in,
                              void* d_out, int out_size, void* d_ws, size_t ws_size,
                              hipStream_t stream) {
  (void)in_sizes; (void)n_in; (void)out_size; (void)ws_size;
  const float* x      = (const float*)d_in[0];
  const float* w_qkv  = (const float*)d_in[1];
  const float* w_proj = (const float*)d_in[2];
  const float* b_proj = (const float*)d_in[3];
  float* out = (float*)d_out;

  // workspace layout (all bf16):
  unsigned short* x_bf     = (unsigned short*)d_ws;                 // 4096x1024
  unsigned short* wqkv_bf  = x_bf    + (size_t)M_ * E_;             // 3072x1024
  unsigned short* wproj_bf = wqkv_bf + (size_t)QKVN * E_;           // 1024x1024
  unsigned short* qkv_bf   = wproj_bf + (size_t)E_ * E_;            // 4096x3072
  unsigned short* attn_bf  = qkv_bf  + (size_t)M_ * QKVN;           // 4096x1024

  int n4;
  n4 = M_ * E_ / 4;
  cvt_f32_to_bf16<<<(n4 + 255) / 256, 256, 0, stream>>>(x, x_bf, n4);
  n4 = QKVN * E_ / 4;
  cvt_f32_to_bf16<<<(n4 + 255) / 256, 256, 0, stream>>>(w_qkv, wqkv_bf, n4);
  n4 = E_ * E_ / 4;
  cvt_f32_to_bf16<<<(n4 + 255) / 256, 256, 0, stream>>>(w_proj, wproj_bf, n4);

  // QKV projection: (4096x1024) @ (3072x1024)^T -> bf16 (4096x3072)
  gemm_bt<1><<<dim3(QKVN / 128, M_ / 128), 256, 0, stream>>>(
      x_bf, wqkv_bf, (void*)qkv_bf, nullptr, M_, QKVN, E_, QKVN);

  // causal attention: 512 blocks, work-paired
  attn_fwd<<<dim3(512), 256, 0, stream>>>(qkv_bf, attn_bf);

  // output projection + bias: (4096x1024) @ (1024x1024)^T + b -> fp32 d_out
  gemm_bt<0><<<dim3(E_ / 128, M_ / 128), 256, 0, stream>>>(
      attn_bf, wproj_bf, (void*)out, b_proj, M_, E_, E_, E_);
}

// Round 4
// 226.577 us; speedup vs baseline: 1.5763x; 1.0771x over previous
//
#include <hip/hip_runtime.h>
#include <hip/hip_bf16.h>

// Problem constants
#define B_    2
#define S_    2048
#define E_    1024
#define H_    16
#define HD_   64
#define M_    (B_ * S_)     // 4096 rows of x
#define QKVN  (3 * E_)      // 3072

typedef __attribute__((ext_vector_type(8))) short  short8;
typedef __attribute__((ext_vector_type(4))) float  f32x4;

static __device__ __forceinline__ unsigned short f2bf(float f) {
  union { float f; unsigned int u; } c; c.f = f;
  unsigned int u = c.u;
  return (unsigned short)((u + 0x7fffu + ((u >> 16) & 1u)) >> 16);  // RNE
}

// async global->LDS, 16B per lane; LDS dest must be wave-uniform base (+lane*16)
static __device__ __forceinline__ void gload16(unsigned short* lds,
                                               const unsigned short* g) {
  __builtin_amdgcn_global_load_lds(
      (__attribute__((address_space(1))) void*)g,
      (__attribute__((address_space(3))) void*)lds, 16, 0, 0);
}

// ---- DPP butterfly reduce within each 16-lane group (VALU pipe, no LDS) ----
// quad_perm[1,0,3,2]=0xB1 (xor1), quad_perm[2,3,0,1]=0x4E (xor2),
// ROW_HALF_MIRROR=0x141 (crosses quads), ROW_MIRROR=0x140 (crosses halves).
static __device__ __forceinline__ float dpp_max16(float x) {
  x = fmaxf(x, __int_as_float(__builtin_amdgcn_update_dpp(
          0, __float_as_int(x), 0xB1, 0xF, 0xF, true)));
  x = fmaxf(x, __int_as_float(__builtin_amdgcn_update_dpp(
          0, __float_as_int(x), 0x4E, 0xF, 0xF, true)));
  x = fmaxf(x, __int_as_float(__builtin_amdgcn_update_dpp(
          0, __float_as_int(x), 0x141, 0xF, 0xF, true)));
  x = fmaxf(x, __int_as_float(__builtin_amdgcn_update_dpp(
          0, __float_as_int(x), 0x140, 0xF, 0xF, true)));
  return x;
}
static __device__ __forceinline__ float dpp_sum16(float x) {
  x += __int_as_float(__builtin_amdgcn_update_dpp(
          0, __float_as_int(x), 0xB1, 0xF, 0xF, true));
  x += __int_as_float(__builtin_amdgcn_update_dpp(
          0, __float_as_int(x), 0x4E, 0xF, 0xF, true));
  x += __int_as_float(__builtin_amdgcn_update_dpp(
          0, __float_as_int(x), 0x141, 0xF, 0xF, true));
  x += __int_as_float(__builtin_amdgcn_update_dpp(
          0, __float_as_int(x), 0x140, 0xF, 0xF, true));
  return x;
}

// ---------------------------------------------------------------------------
// fp32 -> bf16 convert (vectorized, 4 elems/thread)
// ---------------------------------------------------------------------------
__global__ __launch_bounds__(256) void cvt_f32_to_bf16(
    const float* __restrict__ in, unsigned short* __restrict__ out, int n4) {
  int i = blockIdx.x * 256 + threadIdx.x;
  if (i < n4) {
    float4 v = reinterpret_cast<const float4*>(in)[i];
    ushort4 r;
    r.x = f2bf(v.x); r.y = f2bf(v.y); r.z = f2bf(v.z); r.w = f2bf(v.w);
    reinterpret_cast<ushort4*>(out)[i] = r;
  }
}

// ---------------------------------------------------------------------------
// C[M,N] = A(MxK, row-major) * Bt(NxK, row-major)^T  (unchanged, known-good)
// ---------------------------------------------------------------------------
template <int BF16_OUT>
__global__ __launch_bounds__(256) void gemm_bt(
    const unsigned short* __restrict__ A, const unsigned short* __restrict__ Bt,
    void* __restrict__ Cout, const float* __restrict__ bias,
    int M, int N, int K, int ldc) {
  __shared__ alignas(16) unsigned short lds_a[128 * 64];  // 16 KB
  __shared__ alignas(16) unsigned short lds_b[128 * 64];  // 16 KB
  const int t  = threadIdx.x;
  const int w  = t >> 6, l = t & 63, g = l >> 4, lr = l & 15;
  const int bm = blockIdx.y * 128, bn = blockIdx.x * 128;
  const int wr = (w >> 1) * 64,  wc = (w & 1) * 64;

  f32x4 acc[4][4] = {};

  for (int k0 = 0; k0 < K; k0 += 64) {
    __syncthreads();
#pragma unroll
    for (int i = 0; i < 4; i++) {
      const int pass = w * 4 + i;            // 0..15 (wave-uniform)
      const int r = pass * 8 + (l >> 3);     // 0..127
      const int c = (l & 7) ^ (r & 7);       // pre-swizzled source chunk
      gload16(lds_a + pass * 512, A + (size_t)(bm + r) * K + k0 + c * 8);
      gload16(lds_b + pass * 512, Bt + (size_t)(bn + r) * K + k0 + c * 8);
    }
    __syncthreads();

    short8 af[4][2], bfr[4][2];
#pragma unroll
    for (int m = 0; m < 4; m++) {
      const int R = wr + m * 16 + lr;
#pragma unroll
      for (int kk = 0; kk < 2; kk++)
        af[m][kk] = *(const short8*)((const char*)lds_a +
            ((R * 128 + kk * 64 + g * 16) ^ ((R & 7) << 4)));
    }
#pragma unroll
    for (int n = 0; n < 4; n++) {
      const int R = wc + n * 16 + lr;
#pragma unroll
      for (int kk = 0; kk < 2; kk++)
        bfr[n][kk] = *(const short8*)((const char*)lds_b +
            ((R * 128 + kk * 64 + g * 16) ^ ((R & 7) << 4)));
    }
#pragma unroll
    for (int m = 0; m < 4; m++)
#pragma unroll
      for (int n = 0; n < 4; n++) {
        acc[m][n] = __builtin_amdgcn_mfma_f32_16x16x32_bf16(
            af[m][0], bfr[n][0], acc[m][n], 0, 0, 0);
        acc[m][n] = __builtin_amdgcn_mfma_f32_16x16x32_bf16(
            af[m][1], bfr[n][1], acc[m][n], 0, 0, 0);
      }
  }

#pragma unroll
  for (int m = 0; m < 4; m++)
#pragma unroll
    for (int n = 0; n < 4; n++)
#pragma unroll
      for (int j = 0; j < 4; j++) {
        const int row = bm + wr + m * 16 + g * 4 + j;
        const int col = bn + wc + n * 16 + lr;
        const float v = acc[m][n][j];
        if constexpr (BF16_OUT) {
          ((unsigned short*)Cout)[(size_t)row * ldc + col] = f2bf(v);
        } else {
          ((float*)Cout)[(size_t)row * ldc + col] = v + bias[col];
        }
      }
}

// ---------------------------------------------------------------------------
// Causal flash attention over interleaved qkv (bf16, layout (B,S,H,3,HD)).
// Round-2 structure (known-good) + two increments:
//   (1) T14 async-STAGE: KV tile t+1 global->regs issued before compute of
//       tile t; regs->LDS written after the end-of-tile barrier.
//   (2) DPP butterfly reduces replace __shfl_xor chains in online softmax.
//   (3) wave-uniform causal compute gate (barriers remain outside the gate).
// ---------------------------------------------------------------------------
__global__ __launch_bounds__(256) void attn_fwd(
    const unsigned short* __restrict__ qkv, unsigned short* __restrict__ attn_out) {
  __shared__ alignas(16) unsigned short lds_k[64 * 64];     // 8 KB  [kv][d]
  __shared__ alignas(16) unsigned short lds_vt[64 * 64];    // 8 KB  [d][kv]
  __shared__ alignas(16) unsigned short lds_p[4][32 * 64];  // 16 KB per-wave P

  const int t = threadIdx.x;
  const int w = t >> 6, l = t & 63, g = (l >> 4) & 3, lr = l & 15;
  const int bid = blockIdx.x;
  const int bh = bid & 31, b = bh >> 4, h = bh & 15;
  const int rr = bid >> 5;                       // 0..15
  const int bx = (rr < 8) ? rr : 23 - rr;        // pair light+heavy per CU
  const int q0 = bx * 128;
  const int qw = q0 + w * 32;
  const unsigned short* base = qkv + (size_t)b * S_ * QKVN + h * (3 * HD_);

  // Q fragments: A-side, lane (g,lr): Q[qw+m*16+lr][g*8 + kk*32 + 0..7]
  short8 qf[2][2];
#pragma unroll
  for (int m = 0; m < 2; m++) {
    const unsigned short* qp = base + (size_t)(qw + m * 16 + lr) * QKVN + g * 8;
    qf[m][0] = *(const short8*)qp;
    qf[m][1] = *(const short8*)(qp + 32);
  }

  f32x4 o[2][4] = {};
  float m_r[2][4], l_r[2][4];
#pragma unroll
  for (int m = 0; m < 2; m++)
#pragma unroll
    for (int j = 0; j < 4; j++) { m_r[m][j] = -3.0e38f; l_r[m][j] = 0.f; }

  const int numt = 2 * bx + 2;  // 64-wide KV tiles covering kv < q0+128
  const int r_st = t >> 3;      // 0..31 staging row base
  const int kc   = t & 7;       // staging 16B column chunk

  // prologue: load KV tile 0 into regs
  short8 kreg[2], vreg[2];
#pragma unroll
  for (int p = 0; p < 2; p++) {
    const unsigned short* kp =
        base + (size_t)(p * 32 + r_st) * QKVN + HD_ + kc * 8;
    kreg[p] = *(const short8*)kp;
    vreg[p] = *(const short8*)(kp + HD_);
  }

  for (int kt = 0; kt < numt; kt++) {
    const int k0 = kt * 64;
    // ---- regs -> LDS (same layout/swizzles as round 2) ----
#pragma unroll
    for (int p = 0; p < 2; p++) {
      const int r = p * 32 + r_st;
      *(short8*)((char*)lds_k + ((r * 128 + kc * 16) ^ ((r & 7) << 4))) = kreg[p];
#pragma unroll
      for (int j = 0; j < 8; j++) {
        const int d = kc * 8 + j;
        const int swz = ((d & 7) ^ ((d >> 3) & 7)) << 4;
        *(unsigned short*)((char*)lds_vt + ((d * 128 + r * 2) ^ swz)) =
            (unsigned short)vreg[p][j];
      }
    }
    // ---- prefetch KV tile kt+1 into regs (latency hides under compute) ----
    if (kt + 1 < numt) {
#pragma unroll
      for (int p = 0; p < 2; p++) {
        const unsigned short* kp =
            base + (size_t)(k0 + 64 + p * 32 + r_st) * QKVN + HD_ + kc * 8;
        kreg[p] = *(const short8*)kp;
        vreg[p] = *(const short8*)(kp + HD_);
      }
    }
    __syncthreads();

    if (k0 <= qw + 31) {  // wave-uniform causal gate
      // ---- scores S[32 q][64 kv] ----
      f32x4 s[2][4];
      __builtin_amdgcn_s_setprio(1);
#pragma unroll
      for (int n = 0; n < 4; n++) {
        const int R = n * 16 + lr;
        short8 b0 = *(const short8*)((const char*)lds_k +
            ((R * 128 + g * 16) ^ ((R & 7) << 4)));
        short8 b1 = *(const short8*)((const char*)lds_k +
            ((R * 128 + 64 + g * 16) ^ ((R & 7) << 4)));
#pragma unroll
        for (int m = 0; m < 2; m++) {
          f32x4 z = {};
          z = __builtin_amdgcn_mfma_f32_16x16x32_bf16(qf[m][0], b0, z, 0, 0, 0);
          z = __builtin_amdgcn_mfma_f32_16x16x32_bf16(qf[m][1], b1, z, 0, 0, 0);
          s[m][n] = z;
        }
      }
      __builtin_amdgcn_s_setprio(0);

      // ---- causal mask (only diag-crossing wave-tiles) ----
      if (k0 + 63 > qw) {
#pragma unroll
        for (int m = 0; m < 2; m++)
#pragma unroll
          for (int n = 0; n < 4; n++) {
            const int kvc = k0 + n * 16 + lr;
#pragma unroll
            for (int j = 0; j < 4; j++) {
              const int qrow = qw + m * 16 + g * 4 + j;
              if (kvc > qrow) s[m][n][j] = -3.0e38f;
            }
          }
      }

      // ---- online softmax (DPP reduces within 16-lane groups) ----
#pragma unroll
      for (int m = 0; m < 2; m++) {
#pragma unroll
        for (int j = 0; j < 4; j++) {
          const float v0 = s[m][0][j] * 0.125f, v1 = s[m][1][j] * 0.125f;
          const float v2 = s[m][2][j] * 0.125f, v3 = s[m][3][j] * 0.125f;
          float mx = dpp_max16(fmaxf(fmaxf(v0, v1), fmaxf(v2, v3)));
          const float mn = fmaxf(m_r[m][j], mx);
          const float c  = __expf(m_r[m][j] - mn);
          m_r[m][j] = mn;
          const float e0 = __expf(v0 - mn), e1 = __expf(v1 - mn);
          const float e2 = __expf(v2 - mn), e3 = __expf(v3 - mn);
          const float sum = dpp_sum16((e0 + e1) + (e2 + e3));
          l_r[m][j] = l_r[m][j] * c + sum;
#pragma unroll
          for (int dt = 0; dt < 4; dt++) o[m][dt][j] *= c;
          const int row = m * 16 + g * 4 + j;
          const int sw  = (row & 7) << 4;
          char* pb = (char*)lds_p[w];
          *(unsigned short*)(pb + ((row * 128 +      lr * 2) ^ sw)) = f2bf(e0);
          *(unsigned short*)(pb + ((row * 128 + 32 + lr * 2) ^ sw)) = f2bf(e1);
          *(unsigned short*)(pb + ((row * 128 + 64 + lr * 2) ^ sw)) = f2bf(e2);
          *(unsigned short*)(pb + ((row * 128 + 96 + lr * 2) ^ sw)) = f2bf(e3);
        }
      }
      // per-wave LDS round-trip: wait for this wave's ds_writes
      __asm__ volatile("s_waitcnt lgkmcnt(0)" ::: "memory");

      // ---- PV: O[32 q][64 d] += P(32x64) @ V(64x64) ----
      __builtin_amdgcn_s_setprio(1);
#pragma unroll
      for (int m = 0; m < 2; m++) {
        const int prow = m * 16 + lr;
        const int psw  = (prow & 7) << 4;
        short8 pf0 = *(const short8*)((const char*)lds_p[w] +
            ((prow * 128 + g * 16) ^ psw));
        short8 pf1 = *(const short8*)((const char*)lds_p[w] +
            ((prow * 128 + 64 + g * 16) ^ psw));
#pragma unroll
        for (int dt = 0; dt < 4; dt++) {
          const int R = dt * 16 + lr;
          const int vsw = ((R & 7) ^ ((R >> 3) & 7)) << 4;
          short8 vf0 = *(const short8*)((const char*)lds_vt +
              ((R * 128 + g * 16) ^ vsw));
          short8 vf1 = *(const short8*)((const char*)lds_vt +
              ((R * 128 + 64 + g * 16) ^ vsw));
          o[m][dt] = __builtin_amdgcn_mfma_f32_16x16x32_bf16(pf0, vf0, o[m][dt], 0, 0, 0);
          o[m][dt] = __builtin_amdgcn_mfma_f32_16x16x32_bf16(pf1, vf1, o[m][dt], 0, 0, 0);
        }
      }
      __builtin_amdgcn_s_setprio(0);
    }

    __syncthreads();
  }

  // ---- epilogue: O / l, write bf16 to (B,S,E) ----
  unsigned short* outp = attn_out + (size_t)b * S_ * E_ + h * HD_;
#pragma unroll
  for (int m = 0; m < 2; m++)
#pragma unroll
    for (int j = 0; j < 4; j++) {
      const float inv = 1.0f / l_r[m][j];
      const int qrow = qw + m * 16 + g * 4 + j;
#pragma unroll
      for (int dt = 0; dt < 4; dt++)
        outp[(size_t)qrow * E_ + dt * 16 + lr] = f2bf(o[m][dt][j] * inv);
    }
}

// ---------------------------------------------------------------------------
extern "C" void kernel_launch(void* const* d_in, const int* in_sizes, int n_in,
                              void* d_out, int out_size, void* d_ws, size_t ws_size,
                              hipStream_t stream) {
  (void)in_sizes; (void)n_in; (void)out_size; (void)ws_size;
  const float* x      = (const float*)d_in[0];
  const float* w_qkv  = (const float*)d_in[1];
  const float* w_proj = (const float*)d_in[2];
  const float* b_proj = (const float*)d_in[3];
  float* out = (float*)d_out;

  // workspace layout (all bf16):
  unsigned short* x_bf     = (unsigned short*)d_ws;                 // 4096x1024
  unsigned short* wqkv_bf  = x_bf    + (size_t)M_ * E_;             // 3072x1024
  unsigned short* wproj_bf = wqkv_bf + (size_t)QKVN * E_;           // 1024x1024
  unsigned short* qkv_bf   = wproj_bf + (size_t)E_ * E_;            // 4096x3072
  unsigned short* attn_bf  = qkv_bf  + (size_t)M_ * QKVN;           // 4096x1024

  int n4;
  n4 = M_ * E_ / 4;
  cvt_f32_to_bf16<<<(n4 + 255) / 256, 256, 0, stream>>>(x, x_bf, n4);
  n4 = QKVN * E_ / 4;
  cvt_f32_to_bf16<<<(n4 + 255) / 256, 256, 0, stream>>>(w_qkv, wqkv_bf, n4);
  n4 = E_ * E_ / 4;
  cvt_f32_to_bf16<<<(n4 + 255) / 256, 256, 0, stream>>>(w_proj, wproj_bf, n4);

  // QKV projection: (4096x1024) @ (3072x1024)^T -> bf16 (4096x3072)
  gemm_bt<1><<<dim3(QKVN / 128, M_ / 128), 256, 0, stream>>>(
      x_bf, wqkv_bf, (void*)qkv_bf, nullptr, M_, QKVN, E_, QKVN);

  // causal attention: 512 blocks, work-paired
  attn_fwd<<<dim3(512), 256, 0, stream>>>(qkv_bf, attn_bf);

  // output projection + bias: (4096x1024) @ (1024x1024)^T + b -> fp32 d_out
  gemm_bt<0><<<dim3(E_ / 128, M_ / 128), 256, 0, stream>>>(
      attn_bf, wproj_bf, (void*)out, b_proj, M_, E_, E_, E_);
}

// Round 5
// 213.189 us; speedup vs baseline: 1.6753x; 1.0628x over previous
//
#include <hip/hip_runtime.h>
#include <hip/hip_bf16.h>

// Problem constants
#define B_    2
#define S_    2048
#define E_    1024
#define H_    16
#define HD_   64
#define M_    (B_ * S_)     // 4096 rows of x
#define QKVN  (3 * E_)      // 3072

typedef __attribute__((ext_vector_type(8))) short  short8;
typedef __attribute__((ext_vector_type(4))) float  f32x4;
typedef __attribute__((ext_vector_type(4))) unsigned short us16x4;

static __device__ __forceinline__ unsigned short f2bf(float f) {
  union { float f; unsigned int u; } c; c.f = f;
  unsigned int u = c.u;
  return (unsigned short)((u + 0x7fffu + ((u >> 16) & 1u)) >> 16);  // RNE
}

// async global->LDS, 16B per lane; LDS dest must be wave-uniform base (+lane*16)
static __device__ __forceinline__ void gload16(unsigned short* lds,
                                               const unsigned short* g) {
  __builtin_amdgcn_global_load_lds(
      (__attribute__((address_space(1))) void*)g,
      (__attribute__((address_space(3))) void*)lds, 16, 0, 0);
}

// ---------------------------------------------------------------------------
// fp32 -> bf16 convert (vectorized, 4 elems/thread)
// ---------------------------------------------------------------------------
__global__ __launch_bounds__(256) void cvt_f32_to_bf16(
    const float* __restrict__ in, unsigned short* __restrict__ out, int n4) {
  int i = blockIdx.x * 256 + threadIdx.x;
  if (i < n4) {
    float4 v = reinterpret_cast<const float4*>(in)[i];
    ushort4 r;
    r.x = f2bf(v.x); r.y = f2bf(v.y); r.z = f2bf(v.z); r.w = f2bf(v.w);
    reinterpret_cast<ushort4*>(out)[i] = r;
  }
}

// ---------------------------------------------------------------------------
// C[M,N] = A(MxK, row-major) * Bt(NxK, row-major)^T  (unchanged, known-good)
// ---------------------------------------------------------------------------
template <int BF16_OUT>
__global__ __launch_bounds__(256) void gemm_bt(
    const unsigned short* __restrict__ A, const unsigned short* __restrict__ Bt,
    void* __restrict__ Cout, const float* __restrict__ bias,
    int M, int N, int K, int ldc) {
  __shared__ alignas(16) unsigned short lds_a[128 * 64];  // 16 KB
  __shared__ alignas(16) unsigned short lds_b[128 * 64];  // 16 KB
  const int t  = threadIdx.x;
  const int w  = t >> 6, l = t & 63, g = l >> 4, lr = l & 15;
  const int bm = blockIdx.y * 128, bn = blockIdx.x * 128;
  const int wr = (w >> 1) * 64,  wc = (w & 1) * 64;

  f32x4 acc[4][4] = {};

  for (int k0 = 0; k0 < K; k0 += 64) {
    __syncthreads();
#pragma unroll
    for (int i = 0; i < 4; i++) {
      const int pass = w * 4 + i;            // 0..15 (wave-uniform)
      const int r = pass * 8 + (l >> 3);     // 0..127
      const int c = (l & 7) ^ (r & 7);       // pre-swizzled source chunk
      gload16(lds_a + pass * 512, A + (size_t)(bm + r) * K + k0 + c * 8);
      gload16(lds_b + pass * 512, Bt + (size_t)(bn + r) * K + k0 + c * 8);
    }
    __syncthreads();

    short8 af[4][2], bfr[4][2];
#pragma unroll
    for (int m = 0; m < 4; m++) {
      const int R = wr + m * 16 + lr;
#pragma unroll
      for (int kk = 0; kk < 2; kk++)
        af[m][kk] = *(const short8*)((const char*)lds_a +
            ((R * 128 + kk * 64 + g * 16) ^ ((R & 7) << 4)));
    }
#pragma unroll
    for (int n = 0; n < 4; n++) {
      const int R = wc + n * 16 + lr;
#pragma unroll
      for (int kk = 0; kk < 2; kk++)
        bfr[n][kk] = *(const short8*)((const char*)lds_b +
            ((R * 128 + kk * 64 + g * 16) ^ ((R & 7) << 4)));
    }
#pragma unroll
    for (int m = 0; m < 4; m++)
#pragma unroll
      for (int n = 0; n < 4; n++) {
        acc[m][n] = __builtin_amdgcn_mfma_f32_16x16x32_bf16(
            af[m][0], bfr[n][0], acc[m][n], 0, 0, 0);
        acc[m][n] = __builtin_amdgcn_mfma_f32_16x16x32_bf16(
            af[m][1], bfr[n][1], acc[m][n], 0, 0, 0);
      }
  }

#pragma unroll
  for (int m = 0; m < 4; m++)
#pragma unroll
    for (int n = 0; n < 4; n++)
#pragma unroll
      for (int j = 0; j < 4; j++) {
        const int row = bm + wr + m * 16 + g * 4 + j;
        const int col = bn + wc + n * 16 + lr;
        const float v = acc[m][n][j];
        if constexpr (BF16_OUT) {
          ((unsigned short*)Cout)[(size_t)row * ldc + col] = f2bf(v);
        } else {
          ((float*)Cout)[(size_t)row * ldc + col] = v + bias[col];
        }
      }
}

// ---------------------------------------------------------------------------
// Causal flash attention, swapped-operand form (lane-local softmax).
//   S^T = mfma(A=K, B=Q): lane (g,lr) holds S[kv=k0+n*16+g*4+j][q=qw+m*16+lr]
//   softmax per q is lane-local: in-lane tree over 16 + shfl_xor(16,32)
//   P stored [q][kv] (cvt_pk + ds_write_b64, GEMM-style XOR swizzle)
//   O^T = mfma(A=V^T-frag, B=P^T-frag): rescale c and 1/l are lane-local
// Staging (K row-major swz, V^T swz), double-buffer-via-regs, causal gate:
// unchanged from round 4 (known-good).
// ---------------------------------------------------------------------------
__global__ __launch_bounds__(256) void attn_fwd(
    const unsigned short* __restrict__ qkv, unsigned short* __restrict__ attn_out) {
  __shared__ alignas(16) unsigned short lds_k[64 * 64];     // 8 KB  [kv][d]
  __shared__ alignas(16) unsigned short lds_vt[64 * 64];    // 8 KB  [d][kv]
  __shared__ alignas(16) unsigned short lds_p[4][32 * 64];  // 16 KB per-wave P

  const int t = threadIdx.x;
  const int w = t >> 6, l = t & 63, g = (l >> 4) & 3, lr = l & 15;
  const int bid = blockIdx.x;
  const int bh = bid & 31, b = bh >> 4, h = bh & 15;
  const int rr = bid >> 5;                       // 0..15
  const int bx = (rr < 8) ? rr : 23 - rr;        // pair light+heavy per CU
  const int q0 = bx * 128;
  const int qw = q0 + w * 32;
  const unsigned short* base = qkv + (size_t)b * S_ * QKVN + h * (3 * HD_);

  // Q fragments (B-side now): lane (g,lr): Q[qw+m*16+lr][g*8 + kk*32 + 0..7]
  short8 qf[2][2];
#pragma unroll
  for (int m = 0; m < 2; m++) {
    const unsigned short* qp = base + (size_t)(qw + m * 16 + lr) * QKVN + g * 8;
    qf[m][0] = *(const short8*)qp;
    qf[m][1] = *(const short8*)(qp + 32);
  }

  // O^T accumulator: o[m][dt][j] = O[q=qw+m*16+lr][d=dt*16+g*4+j]
  f32x4 o[2][4] = {};
  float m_r[2] = {-3.0e38f, -3.0e38f};  // running max, log2 domain (lane-local q)
  float l_r[2] = {0.f, 0.f};
  const float SCALE2 = 0.18033688011112042f;  // 0.125 * log2(e)

  const int numt = 2 * bx + 2;  // 64-wide KV tiles covering kv < q0+128
  const int r_st = t >> 3;      // 0..31 staging row base
  const int kc   = t & 7;       // staging 16B column chunk

  // prologue: load KV tile 0 into regs
  short8 kreg[2], vreg[2];
#pragma unroll
  for (int p = 0; p < 2; p++) {
    const unsigned short* kp =
        base + (size_t)(p * 32 + r_st) * QKVN + HD_ + kc * 8;
    kreg[p] = *(const short8*)kp;
    vreg[p] = *(const short8*)(kp + HD_);
  }

  for (int kt = 0; kt < numt; kt++) {
    const int k0 = kt * 64;
    // ---- regs -> LDS (same layout/swizzles as round 4) ----
#pragma unroll
    for (int p = 0; p < 2; p++) {
      const int r = p * 32 + r_st;
      *(short8*)((char*)lds_k + ((r * 128 + kc * 16) ^ ((r & 7) << 4))) = kreg[p];
#pragma unroll
      for (int j = 0; j < 8; j++) {
        const int d = kc * 8 + j;
        const int swz = ((d & 7) ^ ((d >> 3) & 7)) << 4;
        *(unsigned short*)((char*)lds_vt + ((d * 128 + r * 2) ^ swz)) =
            (unsigned short)vreg[p][j];
      }
    }
    // ---- prefetch KV tile kt+1 into regs (latency hides under compute) ----
    if (kt + 1 < numt) {
#pragma unroll
      for (int p = 0; p < 2; p++) {
        const unsigned short* kp =
            base + (size_t)(k0 + 64 + p * 32 + r_st) * QKVN + HD_ + kc * 8;
        kreg[p] = *(const short8*)kp;
        vreg[p] = *(const short8*)(kp + HD_);
      }
    }
    __syncthreads();

    if (k0 <= qw + 31) {  // wave-uniform causal gate
      // ---- S^T[64 kv][32 q] = K·Q^T (swapped operands) ----
      f32x4 st[2][4];
      __builtin_amdgcn_s_setprio(1);
#pragma unroll
      for (int n = 0; n < 4; n++) {
        const int R = n * 16 + lr;
        const int sw = (R & 7) << 4;
        short8 kf0 = *(const short8*)((const char*)lds_k +
            ((R * 128 + g * 16) ^ sw));
        short8 kf1 = *(const short8*)((const char*)lds_k +
            ((R * 128 + 64 + g * 16) ^ sw));
#pragma unroll
        for (int m = 0; m < 2; m++) {
          f32x4 z = {};
          z = __builtin_amdgcn_mfma_f32_16x16x32_bf16(kf0, qf[m][0], z, 0, 0, 0);
          z = __builtin_amdgcn_mfma_f32_16x16x32_bf16(kf1, qf[m][1], z, 0, 0, 0);
          st[m][n] = z;
        }
      }
      __builtin_amdgcn_s_setprio(0);

      const bool diag = (k0 + 63 > qw);

      // ---- lane-local softmax (q = qw+m*16+lr) + packed P writes ----
#pragma unroll
      for (int m = 0; m < 2; m++) {
        const int qrow = qw + m * 16 + lr;
        // mask (diag-crossing tiles only) + raw row max
        if (diag) {
#pragma unroll
          for (int n = 0; n < 4; n++)
#pragma unroll
            for (int j = 0; j < 4; j++)
              if ((k0 + n * 16 + g * 4 + j) > qrow) st[m][n][j] = -3.0e38f;
        }
        float mx = st[m][0][0];
#pragma unroll
        for (int n = 0; n < 4; n++)
#pragma unroll
          for (int j = 0; j < 4; j++) mx = fmaxf(mx, st[m][n][j]);
        mx = fmaxf(mx, __shfl_xor(mx, 16, 64));
        mx = fmaxf(mx, __shfl_xor(mx, 32, 64));
        const float mn = fmaxf(m_r[m], mx * SCALE2);
        const float c  = exp2f(m_r[m] - mn);
        m_r[m] = mn;
        float p[4][4];
        float sum = 0.f;
#pragma unroll
        for (int n = 0; n < 4; n++)
#pragma unroll
          for (int j = 0; j < 4; j++) {
            p[n][j] = exp2f(fmaf(st[m][n][j], SCALE2, -mn));
            sum += p[n][j];
          }
        sum += __shfl_xor(sum, 16, 64);
        sum += __shfl_xor(sum, 32, 64);
        l_r[m] = l_r[m] * c + sum;
#pragma unroll
        for (int dt = 0; dt < 4; dt++) o[m][dt] *= c;
        // P[q][kv] -> per-wave LDS: pack j-pairs, ds_write_b64 per n
        char* pb = (char*)lds_p[w];
        const int rowb = (m * 16 + lr) * 128;
        const int sw   = (lr & 7) << 4;
#pragma unroll
        for (int n = 0; n < 4; n++) {
          unsigned w0, w1;
          __asm__("v_cvt_pk_bf16_f32 %0, %1, %2"
                  : "=v"(w0) : "v"(p[n][0]), "v"(p[n][1]));
          __asm__("v_cvt_pk_bf16_f32 %0, %1, %2"
                  : "=v"(w1) : "v"(p[n][2]), "v"(p[n][3]));
          uint2 val; val.x = w0; val.y = w1;
          *(uint2*)(pb + ((rowb + n * 32 + g * 8) ^ sw)) = val;
        }
      }
      // per-wave LDS round-trip: wait for this wave's ds_writes
      __asm__ volatile("s_waitcnt lgkmcnt(0)" ::: "memory");

      // ---- PV: O^T += V^T(64d x 64kv) · P^T(64kv x 32q) ----
      // P^T B-frag: lane (g,lr): P[q=m*16+lr][kv=g*8+0..7 (+32*kk)]
      short8 pf[2][2];
#pragma unroll
      for (int m = 0; m < 2; m++) {
        const int rowb = (m * 16 + lr) * 128;
        const int sw   = (lr & 7) << 4;
        pf[m][0] = *(const short8*)((const char*)lds_p[w] +
            ((rowb + g * 16) ^ sw));
        pf[m][1] = *(const short8*)((const char*)lds_p[w] +
            ((rowb + 64 + g * 16) ^ sw));
      }
      __builtin_amdgcn_s_setprio(1);
#pragma unroll
      for (int dt = 0; dt < 4; dt++) {
        const int R = dt * 16 + lr;
        const int vsw = ((R & 7) ^ ((R >> 3) & 7)) << 4;
        short8 vf0 = *(const short8*)((const char*)lds_vt +
            ((R * 128 + g * 16) ^ vsw));
        short8 vf1 = *(const short8*)((const char*)lds_vt +
            ((R * 128 + 64 + g * 16) ^ vsw));
#pragma unroll
        for (int m = 0; m < 2; m++) {
          o[m][dt] = __builtin_amdgcn_mfma_f32_16x16x32_bf16(
              vf0, pf[m][0], o[m][dt], 0, 0, 0);
          o[m][dt] = __builtin_amdgcn_mfma_f32_16x16x32_bf16(
              vf1, pf[m][1], o[m][dt], 0, 0, 0);
        }
      }
      __builtin_amdgcn_s_setprio(0);
    }

    __syncthreads();
  }

  // ---- epilogue: O = O^T scaled by lane-local 1/l, 8B stores ----
  unsigned short* outp = attn_out + (size_t)b * S_ * E_ + h * HD_;
#pragma unroll
  for (int m = 0; m < 2; m++) {
    const float inv = 1.0f / l_r[m];
    const int qrow = qw + m * 16 + lr;
#pragma unroll
    for (int dt = 0; dt < 4; dt++) {
      us16x4 w4;
#pragma unroll
      for (int j = 0; j < 4; j++) w4[j] = f2bf(o[m][dt][j] * inv);
      *(us16x4*)(outp + (size_t)qrow * E_ + dt * 16 + g * 4) = w4;
    }
  }
}

// ---------------------------------------------------------------------------
extern "C" void kernel_launch(void* const* d_in, const int* in_sizes, int n_in,
                              void* d_out, int out_size, void* d_ws, size_t ws_size,
                              hipStream_t stream) {
  (void)in_sizes; (void)n_in; (void)out_size; (void)ws_size;
  const float* x      = (const float*)d_in[0];
  const float* w_qkv  = (const float*)d_in[1];
  const float* w_proj = (const float*)d_in[2];
  const float* b_proj = (const float*)d_in[3];
  float* out = (float*)d_out;

  // workspace layout (all bf16):
  unsigned short* x_bf     = (unsigned short*)d_ws;                 // 4096x1024
  unsigned short* wqkv_bf  = x_bf    + (size_t)M_ * E_;             // 3072x1024
  unsigned short* wproj_bf = wqkv_bf + (size_t)QKVN * E_;           // 1024x1024
  unsigned short* qkv_bf   = wproj_bf + (size_t)E_ * E_;            // 4096x3072
  unsigned short* attn_bf  = qkv_bf  + (size_t)M_ * QKVN;           // 4096x1024

  int n4;
  n4 = M_ * E_ / 4;
  cvt_f32_to_bf16<<<(n4 + 255) / 256, 256, 0, stream>>>(x, x_bf, n4);
  n4 = QKVN * E_ / 4;
  cvt_f32_to_bf16<<<(n4 + 255) / 256, 256, 0, stream>>>(w_qkv, wqkv_bf, n4);
  n4 = E_ * E_ / 4;
  cvt_f32_to_bf16<<<(n4 + 255) / 256, 256, 0, stream>>>(w_proj, wproj_bf, n4);

  // QKV projection: (4096x1024) @ (3072x1024)^T -> bf16 (4096x3072)
  gemm_bt<1><<<dim3(QKVN / 128, M_ / 128), 256, 0, stream>>>(
      x_bf, wqkv_bf, (void*)qkv_bf, nullptr, M_, QKVN, E_, QKVN);

  // causal attention: 512 blocks, work-paired
  attn_fwd<<<dim3(512), 256, 0, stream>>>(qkv_bf, attn_bf);

  // output projection + bias: (4096x1024) @ (1024x1024)^T + b -> fp32 d_out
  gemm_bt<0><<<dim3(E_ / 128, M_ / 128), 256, 0, stream>>>(
      attn_bf, wproj_bf, (void*)out, b_proj, M_, E_, E_, E_);
}